// Round 2
// baseline (412.442 us; speedup 1.0000x reference)
//
#include <hip/hip_runtime.h>
#include <stdint.h>

#define TT  512
#define BT  8     // batch tile per workgroup -> 512 workgroups -> 2 wg/CU

typedef float  f32x4  __attribute__((ext_vector_type(4)));
typedef short  s16x8  __attribute__((ext_vector_type(8)));
typedef __bf16 bf16x8 __attribute__((ext_vector_type(8)));

#define MFMA_BF16(A, B, C) \
    __builtin_amdgcn_mfma_f32_16x16x32_bf16( \
        __builtin_bit_cast(bf16x8, (A)), __builtin_bit_cast(bf16x8, (B)), (C), 0, 0, 0)

#define LOG2E  1.442695040888963f
#define LOG2E2 2.885390081777927f

__device__ __forceinline__ unsigned short bf16_trunc_bits(float v) {
    union { float f; unsigned u; } x; x.f = v;
    return (unsigned short)(x.u >> 16);
}
__device__ __forceinline__ float bf16_hi_f32(float v) {
    union { float f; unsigned u; } x; x.f = v;
    x.u &= 0xffff0000u;
    return x.f;
}
__device__ __forceinline__ unsigned short bf16_rne_bits(float v) {
    union { float f; unsigned u; } x; x.f = v;
    unsigned r = x.u + 0x7fffu + ((x.u >> 16) & 1u);
    return (unsigned short)(r >> 16);
}

// One workgroup = 8 batches, 4 waves; wave w owns hidden cols [16w, 16w+16).
// Precision split stacked along MFMA M: A rows 0-7 = h_hi(batch), rows 8-15 =
// h_lo(batch). A x Bhi + A x Blo over 2 K-chunks = 12 MFMAs/step covers all
// cross terms. Pre-act = D[m] + D[m+8] via shfl_xor(32). Gate scales
// (-log2e, 2log2e) folded into W_hh/biases; halved bias in acc-init so the
// cross-half combine restores it. h round-trips LDS in A-frag order (dbuf).
__global__ __launch_bounds__(256, 2) void gru_scan_kernel(
    const float* __restrict__ x,     // (4096, 512, 1)
    const float* __restrict__ Wih,   // (192, 1)
    const float* __restrict__ Whh,   // (192, 64)
    const float* __restrict__ bih,   // (192)
    const float* __restrict__ bhh,   // (192)
    const float* __restrict__ Wout,  // (1, 64)
    const float* __restrict__ bout,  // (1)
    float* __restrict__ out)         // (4096, 1)
{
    __shared__ __align__(16) float xs2[TT * BT];          // x transposed: [t][b], 16 KB
    __shared__ __align__(16) short hbuf[2][2][64][8];     // [dbuf][Kchunk][slot][8], 4 KB
    __shared__ float outp[4][BT];

    const int tid  = threadIdx.x;
    const int w    = tid >> 6;
    const int L    = tid & 63;
    const int n16  = L & 15;
    const int quad = L >> 4;
    const int q    = w * 16 + n16;     // hidden col owned by this lane
    const int b0   = blockIdx.x * BT;

    // ---- stage x transposed: xs2[t][b] ----
    {
        #pragma unroll
        for (int k = 0; k < 4; ++k) {
            int idx   = tid + k * 256;       // 0..1023
            int row   = idx >> 7;            // batch row 0..7
            int tq    = idx & 127;           // t/4
            f32x4 v = *(const f32x4*)(x + (size_t)(b0 + row) * TT + tq * 4);
            #pragma unroll
            for (int i = 0; i < 4; ++i)
                xs2[(tq * 4 + i) * BT + row] = v[i];
        }
    }
    // ---- zero both h double-buffers ----
    {
        f32x4* hb = (f32x4*)hbuf;  // 4096 B = 256 f32x4
        f32x4 zv = {0.f, 0.f, 0.f, 0.f};
        hb[tid] = zv;
    }

    // ---- per-lane constants (gate scales folded) ----
    const float wr2   = -LOG2E * Wih[q];
    const float wz2   = -LOG2E * Wih[64 + q];
    const float wn2   =  LOG2E2 * Wih[128 + q];
    const float bR2   = -LOG2E * 0.5f * (bih[q]       + bhh[q]);
    const float bZ2   = -LOG2E * 0.5f * (bih[64 + q]  + bhh[64 + q]);
    const float bN2   =  LOG2E2 * 0.5f * bhh[128 + q];
    const float bihn2 =  LOG2E2 * bih[128 + q];
    const float wo    = Wout[q];

    // ---- W_hh B-fragments (scaled), split hi(trunc)+lo(rne) bf16 ----
    s16x8 Bhi[3][2], Blo[3][2];
    #pragma unroll
    for (int g = 0; g < 3; ++g) {
        const float sg = (g == 2) ? LOG2E2 : -LOG2E;
        #pragma unroll
        for (int c = 0; c < 2; ++c) {
            const float* p = Whh + ((g * 64 + q) * 64 + c * 32 + quad * 8);
            #pragma unroll
            for (int j = 0; j < 8; ++j) {
                float v   = p[j] * sg;
                float hif = bf16_hi_f32(v);
                Bhi[g][c][j] = (short)bf16_trunc_bits(v);
                Blo[g][c][j] = (short)bf16_rne_bits(v - hif);
            }
        }
    }

    // persistent h (fp32); lane holds batches mb = (quad&1)*4 + reg
    // (quads 2,3 are bit-exact duplicates of quads 0,1)
    float hD[4] = {0.f, 0.f, 0.f, 0.f};

    // writer-side A-layout address for col q
    const int cw  = q >> 5;          // K-chunk
    const int qd  = (q & 31) >> 3;   // 8-wide k-group within chunk
    const int jw  = q & 7;           // element within group
    const int mrowb = (quad & 1) * 4 + ((quad >> 1) << 3);  // +8 rows for lo-writers
    const int isLo  = quad >> 1;

    short* hflat = (short*)hbuf;
    const s16x8* hbv = (const s16x8*)hbuf;   // dbuf stride 128, chunk stride 64

    int cur = 0;
    for (int t = 0; t < TT; ++t) {
        __syncthreads();

        s16x8 A0 = hbv[cur * 128 +  0 + L];
        s16x8 A1 = hbv[cur * 128 + 64 + L];

        f32x4 aR = {bR2, bR2, bR2, bR2};
        f32x4 aZ = {bZ2, bZ2, bZ2, bZ2};
        f32x4 aN = {bN2, bN2, bN2, bN2};

        aR = MFMA_BF16(A0, Bhi[0][0], aR);
        aZ = MFMA_BF16(A0, Bhi[1][0], aZ);
        aN = MFMA_BF16(A0, Bhi[2][0], aN);
        aR = MFMA_BF16(A1, Bhi[0][1], aR);
        aZ = MFMA_BF16(A1, Bhi[1][1], aZ);
        aN = MFMA_BF16(A1, Bhi[2][1], aN);
        aR = MFMA_BF16(A0, Blo[0][0], aR);
        aZ = MFMA_BF16(A0, Blo[1][0], aZ);
        aN = MFMA_BF16(A0, Blo[2][0], aN);
        aR = MFMA_BF16(A1, Blo[0][1], aR);
        aZ = MFMA_BF16(A1, Blo[1][1], aZ);
        aN = MFMA_BF16(A1, Blo[2][1], aN);

        const int nxt = cur ^ 1;
        short* wp = hflat + nxt * 1024 + cw * 512 + (qd * 16 + mrowb) * 8 + jw;

        const f32x4 xq = *(const f32x4*)(xs2 + t * BT + (quad & 1) * 4);

        #pragma unroll
        for (int reg = 0; reg < 4; ++reg) {
            float pR = aR[reg] + __shfl_xor(aR[reg], 32, 64);
            float pZ = aZ[reg] + __shfl_xor(aZ[reg], 32, 64);
            float pN = aN[reg] + __shfl_xor(aN[reg], 32, 64);
            float xv = xq[reg];
            float ar = __builtin_fmaf(xv, wr2, pR);
            float az = __builtin_fmaf(xv, wz2, pZ);
            float r  = __builtin_amdgcn_rcpf(1.0f + __builtin_amdgcn_exp2f(ar));
            float z  = __builtin_amdgcn_rcpf(1.0f + __builtin_amdgcn_exp2f(az));
            float an = __builtin_fmaf(r, pN, __builtin_fmaf(xv, wn2, bihn2));
            float n  = __builtin_fmaf(-2.0f,
                         __builtin_amdgcn_rcpf(__builtin_amdgcn_exp2f(an) + 1.0f), 1.0f);
            float h  = __builtin_fmaf(z, hD[reg] - n, n);
            hD[reg] = h;

            unsigned short hib = bf16_trunc_bits(h);
            float lo  = h - bf16_hi_f32(h);          // exact residual
            unsigned short lob = bf16_trunc_bits(lo);
            wp[reg * 8] = (short)(isLo ? lob : hib);
        }
        cur = nxt;
    }

    // ---- epilogue: out[b] = sum_q h[b][q]*Wout[q] + bout ----
    float p[4];
    #pragma unroll
    for (int reg = 0; reg < 4; ++reg) p[reg] = hD[reg] * wo;
    #pragma unroll
    for (int mask = 1; mask <= 8; mask <<= 1) {
        #pragma unroll
        for (int reg = 0; reg < 4; ++reg)
            p[reg] += __shfl_xor(p[reg], mask, 64);
    }
    if (n16 == 0 && quad < 2) {
        #pragma unroll
        for (int reg = 0; reg < 4; ++reg)
            outp[w][quad * 4 + reg] = p[reg];
    }
    __syncthreads();
    if (tid < BT) {
        out[b0 + tid] = outp[0][tid] + outp[1][tid] + outp[2][tid] + outp[3][tid] + bout[0];
    }
}

extern "C" void kernel_launch(void* const* d_in, const int* in_sizes, int n_in,
                              void* d_out, int out_size, void* d_ws, size_t ws_size,
                              hipStream_t stream) {
    (void)in_sizes; (void)n_in; (void)d_ws; (void)ws_size; (void)out_size;
    const float* x    = (const float*)d_in[0];
    const float* Wih  = (const float*)d_in[1];
    const float* Whh  = (const float*)d_in[2];
    const float* bih  = (const float*)d_in[3];
    const float* bhh  = (const float*)d_in[4];
    const float* Wout = (const float*)d_in[5];
    const float* bout = (const float*)d_in[6];
    float* out = (float*)d_out;

    gru_scan_kernel<<<dim3(4096 / BT), dim3(256), 0, stream>>>(
        x, Wih, Whh, bih, bhh, Wout, bout, out);
}

// Round 3
// 284.281 us; speedup vs baseline: 1.4508x; 1.4508x over previous
//
#include <hip/hip_runtime.h>
#include <stdint.h>

#define TT 512
#define BT 16   // 4096/16 = 256 wgs = 1 wg/CU (pinned by batch count)

typedef float  f32x4  __attribute__((ext_vector_type(4)));
typedef float  f32x2  __attribute__((ext_vector_type(2)));
typedef short  s16x8  __attribute__((ext_vector_type(8)));
typedef __bf16 bf16x8 __attribute__((ext_vector_type(8)));

#define MFMA_BF16(A, B, C) \
    __builtin_amdgcn_mfma_f32_16x16x32_bf16( \
        __builtin_bit_cast(bf16x8, (A)), __builtin_bit_cast(bf16x8, (B)), (C), 0, 0, 0)

#define LOG2E  1.442695040888963f
#define LOG2E2 2.885390081777927f

static __device__ __forceinline__ unsigned bits(float v) {
    union { float f; unsigned u; } x; x.f = v; return x.u;
}
static __device__ __forceinline__ float fbits(unsigned u) {
    union { unsigned u; float f; } x; x.u = u; return x.f;
}
static __device__ __forceinline__ unsigned short bf16_rne_bits(float v) {
    unsigned u = bits(v);
    unsigned r = u + 0x7fffu + ((u >> 16) & 1u);
    return (unsigned short)(r >> 16);
}

// R1 structure (BT=16, 4 waves, wave w owns cols [16w,16w+16), 18 MFMA/step)
// + elementwise diet: folded log2 scales, shared rcp for r/z, packed-f32-
// friendly f32x2 math, trunc hi/lo pack, broadcast b128 x reads, unroll-2.
__global__ __launch_bounds__(256) void gru_scan_kernel(
    const float* __restrict__ x,     // (4096, 512, 1)
    const float* __restrict__ Wih,   // (192, 1)
    const float* __restrict__ Whh,   // (192, 64)
    const float* __restrict__ bih,   // (192)
    const float* __restrict__ bhh,   // (192)
    const float* __restrict__ Wout,  // (1, 64)
    const float* __restrict__ bout,  // (1)
    float* __restrict__ out)         // (4096, 1)
{
    __shared__ __align__(16) float xs2[TT * BT];     // x transposed [t][b], 32 KB
    // [f = dbuf*4 + hl*2 + chunk][slot = kgroup*16 + m][8 shorts] : A-frag order
    __shared__ __align__(16) short hbuf[8][64][8];   // 8 KB
    __shared__ float outp[4][BT];

    const int tid  = threadIdx.x;
    const int w    = tid >> 6;
    const int L    = tid & 63;
    const int n16  = L & 15;
    const int quad = L >> 4;
    const int q    = w * 16 + n16;   // hidden col owned by this lane
    const int b0   = blockIdx.x * BT;

    // ---- stage x transposed: xs2[t][b] ----
    #pragma unroll
    for (int k = 0; k < 8; ++k) {
        int idx = tid + k * 256;          // 0..2047
        int row = idx >> 7;               // batch row 0..15
        int t4  = idx & 127;              // t/4
        f32x4 v = *(const f32x4*)(x + (size_t)(b0 + row) * TT + t4 * 4);
        #pragma unroll
        for (int i = 0; i < 4; ++i)
            xs2[(t4 * 4 + i) * BT + row] = v[i];
    }
    // ---- zero both h double-buffers ----
    {
        f32x4* hb = (f32x4*)hbuf;   // 8192 B = 512 f32x4
        f32x4 zv = {0.f, 0.f, 0.f, 0.f};
        hb[tid] = zv; hb[tid + 256] = zv;
    }

    // ---- per-lane constants (gate scales folded: r,z get -log2e; n gets 2log2e) ----
    const float wr2   = -LOG2E  * Wih[q];
    const float wz2   = -LOG2E  * Wih[64 + q];
    const float wn2   =  LOG2E2 * Wih[128 + q];
    const float bR2   = -LOG2E  * (bih[q]      + bhh[q]);
    const float bZ2   = -LOG2E  * (bih[64 + q] + bhh[64 + q]);
    const float bN2   =  LOG2E2 * bhh[128 + q];
    const float bihn2 =  LOG2E2 * bih[128 + q];
    const float wo    = Wout[q];

    // ---- W_hh B-fragments (scaled), split hi(trunc)+lo(rne) bf16 ----
    s16x8 Bhi[3][2], Blo[3][2];
    #pragma unroll
    for (int g = 0; g < 3; ++g) {
        const float sg = (g == 2) ? LOG2E2 : -LOG2E;
        #pragma unroll
        for (int c = 0; c < 2; ++c) {
            const float* p = Whh + ((g * 64 + q) * 64 + c * 32 + quad * 8);
            #pragma unroll
            for (int j = 0; j < 8; ++j) {
                float v   = p[j] * sg;
                float hif = fbits(bits(v) & 0xffff0000u);
                Bhi[g][c][j] = (short)(bits(v) >> 16);
                Blo[g][c][j] = (short)bf16_rne_bits(v - hif);
            }
        }
    }

    // persistent h (fp32), D-layout: reg -> (m = quad*4+reg, col q)
    float hD[4] = {0.f, 0.f, 0.f, 0.f};

    // writer-side A-layout address pieces for col q (k-index of next matmul)
    const int cw = q >> 5;           // chunk
    const int qd = (q & 31) >> 3;    // k-group
    const int jw = q & 7;            // element within group

    const s16x8* hbv = (const s16x8*)hbuf;

    auto step = [&](int cur, int t) {
        __syncthreads();

        s16x8 Ah0 = hbv[cur * 256 +   0 + L];
        s16x8 Ah1 = hbv[cur * 256 +  64 + L];
        s16x8 Al0 = hbv[cur * 256 + 128 + L];
        s16x8 Al1 = hbv[cur * 256 + 192 + L];
        f32x4 xq  = *(const f32x4*)(xs2 + t * BT + quad * 4);  // broadcast per quad

        f32x4 aR = {bR2, bR2, bR2, bR2};
        f32x4 aZ = {bZ2, bZ2, bZ2, bZ2};
        f32x4 aN = {bN2, bN2, bN2, bN2};

        aR = MFMA_BF16(Ah0, Bhi[0][0], aR); aZ = MFMA_BF16(Ah0, Bhi[1][0], aZ); aN = MFMA_BF16(Ah0, Bhi[2][0], aN);
        aR = MFMA_BF16(Ah1, Bhi[0][1], aR); aZ = MFMA_BF16(Ah1, Bhi[1][1], aZ); aN = MFMA_BF16(Ah1, Bhi[2][1], aN);
        aR = MFMA_BF16(Ah0, Blo[0][0], aR); aZ = MFMA_BF16(Ah0, Blo[1][0], aZ); aN = MFMA_BF16(Ah0, Blo[2][0], aN);
        aR = MFMA_BF16(Ah1, Blo[0][1], aR); aZ = MFMA_BF16(Ah1, Blo[1][1], aZ); aN = MFMA_BF16(Ah1, Blo[2][1], aN);
        aR = MFMA_BF16(Al0, Bhi[0][0], aR); aZ = MFMA_BF16(Al0, Bhi[1][0], aZ); aN = MFMA_BF16(Al0, Bhi[2][0], aN);
        aR = MFMA_BF16(Al1, Bhi[0][1], aR); aZ = MFMA_BF16(Al1, Bhi[1][1], aZ); aN = MFMA_BF16(Al1, Bhi[2][1], aN);

        const int nxt = cur ^ 1;
        short* wh = (short*)hbuf + nxt * 2048 + cw * 512 + qd * 128 + jw;
        short* wl = wh + 1024;   // hl stride = 2*512 shorts

        #pragma unroll
        for (int p = 0; p < 4; p += 2) {
            f32x2 aRp = {aR[p], aR[p + 1]};
            f32x2 aZp = {aZ[p], aZ[p + 1]};
            f32x2 aNp = {aN[p], aN[p + 1]};
            f32x2 xv  = {xq[p], xq[p + 1]};
            f32x2 hp  = {hD[p], hD[p + 1]};

            f32x2 ar = xv * wr2 + aRp;      // pk_fma
            f32x2 az = xv * wz2 + aZp;
            f32x2 Er = {__builtin_amdgcn_exp2f(ar[0]), __builtin_amdgcn_exp2f(ar[1])};
            f32x2 Ez = {__builtin_amdgcn_exp2f(az[0]), __builtin_amdgcn_exp2f(az[1])};
            f32x2 DR = Er + 1.0f;
            f32x2 DZ = Ez + 1.0f;
            f32x2 P  = DR * DZ;             // bounded: |preact'| <= ~26 -> no overflow
            f32x2 ip = {__builtin_amdgcn_rcpf(P[0]), __builtin_amdgcn_rcpf(P[1])};
            f32x2 r  = ip * DZ;             // = 1/DR
            f32x2 z  = ip * DR;             // = 1/DZ
            f32x2 xn = xv * wn2 + bihn2;
            f32x2 an = r * aNp + xn;
            f32x2 En = {__builtin_amdgcn_exp2f(an[0]), __builtin_amdgcn_exp2f(an[1])};
            f32x2 DN = En + 1.0f;
            f32x2 rn = {__builtin_amdgcn_rcpf(DN[0]), __builtin_amdgcn_rcpf(DN[1])};
            f32x2 n  = rn * -2.0f + 1.0f;   // tanh
            f32x2 hn = z * (hp - n) + n;    // (1-z)n + z h

            hD[p] = hn[0]; hD[p + 1] = hn[1];

            unsigned u0 = bits(hn[0]), u1 = bits(hn[1]);
            float lo0 = hn[0] - fbits(u0 & 0xffff0000u);
            float lo1 = hn[1] - fbits(u1 & 0xffff0000u);
            const int m0 = quad * 4 + p;
            wh[m0 * 8]       = (short)(u0 >> 16);
            wh[(m0 + 1) * 8] = (short)(u1 >> 16);
            wl[m0 * 8]       = (short)(bits(lo0) >> 16);
            wl[(m0 + 1) * 8] = (short)(bits(lo1) >> 16);
        }
    };

    for (int t = 0; t < TT; t += 2) {
        step(0, t);
        step(1, t + 1);
    }

    // ---- epilogue: out[b] = sum_q h[b][q]*Wout[q] + bout ----
    float p[4];
    #pragma unroll
    for (int reg = 0; reg < 4; ++reg) p[reg] = hD[reg] * wo;
    #pragma unroll
    for (int mask = 1; mask <= 8; mask <<= 1) {
        #pragma unroll
        for (int reg = 0; reg < 4; ++reg)
            p[reg] += __shfl_xor(p[reg], mask, 64);
    }
    if (n16 == 0) {
        #pragma unroll
        for (int reg = 0; reg < 4; ++reg)
            outp[w][quad * 4 + reg] = p[reg];
    }
    __syncthreads();
    if (tid < BT) {
        out[b0 + tid] = outp[0][tid] + outp[1][tid] + outp[2][tid] + outp[3][tid] + bout[0];
    }
}

extern "C" void kernel_launch(void* const* d_in, const int* in_sizes, int n_in,
                              void* d_out, int out_size, void* d_ws, size_t ws_size,
                              hipStream_t stream) {
    (void)in_sizes; (void)n_in; (void)d_ws; (void)ws_size; (void)out_size;
    const float* x    = (const float*)d_in[0];
    const float* Wih  = (const float*)d_in[1];
    const float* Whh  = (const float*)d_in[2];
    const float* bih  = (const float*)d_in[3];
    const float* bhh  = (const float*)d_in[4];
    const float* Wout = (const float*)d_in[5];
    const float* bout = (const float*)d_in[6];
    float* out = (float*)d_out;

    gru_scan_kernel<<<dim3(4096 / BT), dim3(256), 0, stream>>>(
        x, Wih, Whh, bih, bhh, Wout, bout, out);
}

// Round 4
// 212.523 us; speedup vs baseline: 1.9407x; 1.3376x over previous
//
#include <hip/hip_runtime.h>
#include <stdint.h>

#define TT 512
#define BT 16   // 4096/16 = 256 wgs = 1 wg/CU (occupancy pinned: 1024 waves total)

typedef float    f32x4 __attribute__((ext_vector_type(4)));
typedef float    f32x2 __attribute__((ext_vector_type(2)));
typedef short    s16x8 __attribute__((ext_vector_type(8)));
typedef _Float16 f16x8 __attribute__((ext_vector_type(8)));

#define MFMA_F16(A, B, C) \
    __builtin_amdgcn_mfma_f32_16x16x32_f16( \
        __builtin_bit_cast(f16x8, (A)), (B), (C), 0, 0, 0)

#define LOG2E  1.442695040888963f
#define LOG2E2 2.885390081777927f

static __device__ __forceinline__ unsigned bits(float v) {
    union { float f; unsigned u; } x; x.f = v; return x.u;
}

// BT=16, 4 waves, wave w owns hidden cols [16w,16w+16).
// fp16 MFMA, no precision split: 6 MFMA/step (3 gates x 2 K-chunks).
// W_hh lives in registers as fp16 B-fragments; h round-trips LDS (fp16,
// A-frag order, double-buffered, 1 barrier/step). Gate scales (-log2e,
// 2log2e) folded into W/biases; shared rcp for r,z; packed f32x2 math.
__global__ __launch_bounds__(256) void gru_scan_kernel(
    const float* __restrict__ x,     // (4096, 512, 1)
    const float* __restrict__ Wih,   // (192, 1)
    const float* __restrict__ Whh,   // (192, 64)
    const float* __restrict__ bih,   // (192)
    const float* __restrict__ bhh,   // (192)
    const float* __restrict__ Wout,  // (1, 64)
    const float* __restrict__ bout,  // (1)
    float* __restrict__ out)         // (4096, 1)
{
    __shared__ __align__(16) float xs2[TT * BT];     // x transposed [t][b], 32 KB
    // [dbuf][Kchunk][slot = kgroup*16 + m][8 f16] : A-frag order, 4 KB
    __shared__ __align__(16) short hbuf[2][2][64][8];
    __shared__ float outp[4][BT];

    const int tid  = threadIdx.x;
    const int w    = tid >> 6;
    const int L    = tid & 63;
    const int n16  = L & 15;
    const int quad = L >> 4;
    const int q    = w * 16 + n16;   // hidden col owned by this lane
    const int b0   = blockIdx.x * BT;

    // ---- stage x transposed: xs2[t][b] ----
    #pragma unroll
    for (int k = 0; k < 8; ++k) {
        int idx = tid + k * 256;          // 0..2047
        int row = idx >> 7;               // batch row 0..15
        int t4  = idx & 127;              // t/4
        f32x4 v = *(const f32x4*)(x + (size_t)(b0 + row) * TT + t4 * 4);
        #pragma unroll
        for (int i = 0; i < 4; ++i)
            xs2[(t4 * 4 + i) * BT + row] = v[i];
    }
    // ---- zero both h double-buffers (4 KB) ----
    if (tid < 256) {
        f32x4* hb = (f32x4*)hbuf;   // 4096 B = 256 f32x4
        f32x4 zv = {0.f, 0.f, 0.f, 0.f};
        hb[tid] = zv;
    }

    // ---- per-lane constants (gate scales folded) ----
    const float wr2   = -LOG2E  * Wih[q];
    const float wz2   = -LOG2E  * Wih[64 + q];
    const float wn2   =  LOG2E2 * Wih[128 + q];
    const float bR2   = -LOG2E  * (bih[q]      + bhh[q]);
    const float bZ2   = -LOG2E  * (bih[64 + q] + bhh[64 + q]);
    const float bN2   =  LOG2E2 * bhh[128 + q];
    const float bihn2 =  LOG2E2 * bih[128 + q];
    const float wo    = Wout[q];

    // ---- W_hh B-fragments (scaled), fp16 RNE ----
    f16x8 Bf[3][2];
    #pragma unroll
    for (int g = 0; g < 3; ++g) {
        const float sg = (g == 2) ? LOG2E2 : -LOG2E;
        #pragma unroll
        for (int c = 0; c < 2; ++c) {
            const float* p = Whh + ((g * 64 + q) * 64 + c * 32 + quad * 8);
            #pragma unroll
            for (int j = 0; j < 8; ++j)
                Bf[g][c][j] = (_Float16)(p[j] * sg);
        }
    }

    // persistent h (fp32), D-layout: reg -> (m = quad*4+reg, col q)
    float hD[4] = {0.f, 0.f, 0.f, 0.f};

    // writer-side A-layout address pieces for col q (k-index of next matmul)
    const int cw = q >> 5;           // K-chunk
    const int qd = (q & 31) >> 3;    // k-group
    const int jw = q & 7;            // element within group

    const s16x8* hbv = (const s16x8*)hbuf;   // dbuf stride 128, chunk stride 64

    auto step = [&](int cur, int t) {
        __syncthreads();

        s16x8 A0 = hbv[cur * 128 +  0 + L];
        s16x8 A1 = hbv[cur * 128 + 64 + L];
        f32x4 xq = *(const f32x4*)(xs2 + t * BT + quad * 4);  // per-quad broadcast

        f32x4 aR = {bR2, bR2, bR2, bR2};
        f32x4 aZ = {bZ2, bZ2, bZ2, bZ2};
        f32x4 aN = {bN2, bN2, bN2, bN2};

        aR = MFMA_F16(A0, Bf[0][0], aR);
        aZ = MFMA_F16(A0, Bf[1][0], aZ);
        aN = MFMA_F16(A0, Bf[2][0], aN);
        aR = MFMA_F16(A1, Bf[0][1], aR);
        aZ = MFMA_F16(A1, Bf[1][1], aZ);
        aN = MFMA_F16(A1, Bf[2][1], aN);

        const int nxt = cur ^ 1;
        short* wh = (short*)hbuf + nxt * 1024 + cw * 512 + qd * 128 + jw;

        #pragma unroll
        for (int p = 0; p < 4; p += 2) {
            f32x2 aRp = {aR[p], aR[p + 1]};
            f32x2 aZp = {aZ[p], aZ[p + 1]};
            f32x2 aNp = {aN[p], aN[p + 1]};
            f32x2 xv  = {xq[p], xq[p + 1]};
            f32x2 hp  = {hD[p], hD[p + 1]};

            f32x2 ar = xv * wr2 + aRp;      // pk_fma
            f32x2 az = xv * wz2 + aZp;
            f32x2 Er = {__builtin_amdgcn_exp2f(ar[0]), __builtin_amdgcn_exp2f(ar[1])};
            f32x2 Ez = {__builtin_amdgcn_exp2f(az[0]), __builtin_amdgcn_exp2f(az[1])};
            f32x2 DR = Er + 1.0f;
            f32x2 DZ = Ez + 1.0f;
            f32x2 P  = DR * DZ;             // bounded preacts -> no overflow
            f32x2 ip = {__builtin_amdgcn_rcpf(P[0]), __builtin_amdgcn_rcpf(P[1])};
            f32x2 r  = ip * DZ;             // = 1/DR = sigmoid(pre_r)
            f32x2 z  = ip * DR;             // = 1/DZ = sigmoid(pre_z)
            f32x2 xn = xv * wn2 + bihn2;
            f32x2 an = r * aNp + xn;
            f32x2 En = {__builtin_amdgcn_exp2f(an[0]), __builtin_amdgcn_exp2f(an[1])};
            f32x2 DN = En + 1.0f;
            f32x2 rn = {__builtin_amdgcn_rcpf(DN[0]), __builtin_amdgcn_rcpf(DN[1])};
            f32x2 n  = rn * -2.0f + 1.0f;   // tanh
            f32x2 hn = z * (hp - n) + n;    // (1-z)n + z h

            hD[p] = hn[0]; hD[p + 1] = hn[1];

            const int m0 = quad * 4 + p;
            wh[m0 * 8]       = __builtin_bit_cast(short, (_Float16)hn[0]);
            wh[(m0 + 1) * 8] = __builtin_bit_cast(short, (_Float16)hn[1]);
        }
    };

    for (int t = 0; t < TT; t += 2) {
        step(0, t);
        step(1, t + 1);
    }

    // ---- epilogue: out[b] = sum_q h[b][q]*Wout[q] + bout ----
    float p[4];
    #pragma unroll
    for (int reg = 0; reg < 4; ++reg) p[reg] = hD[reg] * wo;
    #pragma unroll
    for (int mask = 1; mask <= 8; mask <<= 1) {
        #pragma unroll
        for (int reg = 0; reg < 4; ++reg)
            p[reg] += __shfl_xor(p[reg], mask, 64);
    }
    if (n16 == 0) {
        #pragma unroll
        for (int reg = 0; reg < 4; ++reg)
            outp[w][quad * 4 + reg] = p[reg];
    }
    __syncthreads();
    if (tid < BT) {
        out[b0 + tid] = outp[0][tid] + outp[1][tid] + outp[2][tid] + outp[3][tid] + bout[0];
    }
}

extern "C" void kernel_launch(void* const* d_in, const int* in_sizes, int n_in,
                              void* d_out, int out_size, void* d_ws, size_t ws_size,
                              hipStream_t stream) {
    (void)in_sizes; (void)n_in; (void)d_ws; (void)ws_size; (void)out_size;
    const float* x    = (const float*)d_in[0];
    const float* Wih  = (const float*)d_in[1];
    const float* Whh  = (const float*)d_in[2];
    const float* bih  = (const float*)d_in[3];
    const float* bhh  = (const float*)d_in[4];
    const float* Wout = (const float*)d_in[5];
    const float* bout = (const float*)d_in[6];
    float* out = (float*)d_out;

    gru_scan_kernel<<<dim3(4096 / BT), dim3(256), 0, stream>>>(
        x, Wih, Whh, bih, bhh, Wout, bout, out);
}